// Round 8
// baseline (118.989 us; speedup 1.0000x reference)
//
#include <hip/hip_runtime.h>
#include <math.h>

#define NB 8
#define NE 128
#define NS 4096
#define CSCALE 0.12751743f   // log2(e)/sqrt(128), folded into Q weights/bias

typedef short s8v __attribute__((ext_vector_type(8)));    // 8 bf16 MFMA A/B frag
typedef float f4v __attribute__((ext_vector_type(4)));    // 16x16 C frag
typedef float f16v __attribute__((ext_vector_type(16)));  // 32x32 C frag
typedef unsigned int u32;
typedef unsigned int u2v __attribute__((ext_vector_type(2)));
typedef __attribute__((address_space(1))) const u32* gp1_t;
typedef __attribute__((address_space(3))) u32* lp3_t;

__device__ __forceinline__ ushort f2bf(float f) {
  union { float f; unsigned u; } v; v.f = f;
  unsigned r = v.u + 0x7fffu + ((v.u >> 16) & 1u);  // RNE
  return (ushort)(r >> 16);
}
__device__ __forceinline__ float bf2f(ushort h) {
  union { unsigned u; float f; } v; v.u = ((unsigned)h) << 16; return v.f;
}
__device__ __forceinline__ void gload_lds16(const void* g, void* l) {
  __builtin_amdgcn_global_load_lds((gp1_t)g, (lp3_t)l, 16, 0, 0);
}
__device__ __forceinline__ u32 cvtpk(float lo, float hi) {
  u32 r;
  asm("v_cvt_pk_bf16_f32 %0, %1, %2" : "=v"(r) : "v"(lo), "v"(hi));
  return r;
}
// split 8 consecutive fp32 into bf16 hi + lo fragments (bf16x3 accuracy)
__device__ __forceinline__ void split8(const float* __restrict__ p, float scale,
                                       s8v& hi, s8v& lo) {
  union { s8v v; ushort u[8]; } H, L;
  #pragma unroll
  for (int i = 0; i < 8; ++i) {
    float v = p[i] * scale;
    ushort h = f2bf(v);
    H.u[i] = h;
    L.u[i] = f2bf(v - bf2f(h));
  }
  hi = H.v; lo = L.v;
}

// ---------------- projection as bf16x3 MFMA GEMM ---------------------------
// outputs: Qn [S][D] (pre-scaled), Kn [S][D], Vt [D][S]; W split done in-reg.
__global__ __launch_bounds__(256, 2) void proj_gemm(
    const float* __restrict__ x,
    const float* __restrict__ Wq, const float* __restrict__ bq,
    const float* __restrict__ Wk, const float* __restrict__ bk,
    const float* __restrict__ Wv, const float* __restrict__ bv,
    ushort* __restrict__ Qn, ushort* __restrict__ Kn, ushort* __restrict__ Vt)
{
  const int tid = threadIdx.x;
  const int wv = tid >> 6, lane = tid & 63;
  const int g = lane >> 4, c = lane & 15;
  const int bid = blockIdx.x;
  const int b = bid & 7;                  // XCD pin
  const int s0 = (bid >> 3) * 64;
  const float* xb = x + (size_t)b * NE * NS;

  __shared__ __align__(16) ushort xh[64][136], xl[64][136];  // x^T tile, hi/lo

  {  // stage: thread owns (s = tid&63, e-chunk), b128 writes
    const int ss = tid & 63, cq = tid >> 6;
    #pragma unroll
    for (int p = 0; p < 4; ++p) {
      const int ch = p * 4 + cq;          // e-chunk 0..15 (8 e each)
      union { s8v v; ushort u[8]; } H, L;
      #pragma unroll
      for (int i = 0; i < 8; ++i) {
        float v = xb[(size_t)(ch * 8 + i) * NS + s0 + ss];
        ushort hi = f2bf(v);
        H.u[i] = hi;
        L.u[i] = f2bf(v - bf2f(hi));
      }
      *(s8v*)&xh[ss][ch * 8] = H.v;
      *(s8v*)&xl[ss][ch * 8] = L.v;
    }
  }
  __syncthreads();

  f4v aq[2][4], ak[2][4], av[2][4];
  #pragma unroll
  for (int i = 0; i < 2; ++i)
    #pragma unroll
    for (int j = 0; j < 4; ++j) {
      aq[i][j] = (f4v){0.f,0.f,0.f,0.f};
      ak[i][j] = (f4v){0.f,0.f,0.f,0.f};
      av[i][j] = (f4v){0.f,0.f,0.f,0.f};
    }

  #pragma unroll
  for (int ks = 0; ks < 4; ++ks) {
    s8v xbh[4], xbl[4];
    #pragma unroll
    for (int st = 0; st < 4; ++st) {
      xbh[st] = *(const s8v*)&xh[st * 16 + c][ks * 32 + g * 8];
      xbl[st] = *(const s8v*)&xl[st * 16 + c][ks * 32 + g * 8];
    }
    #pragma unroll
    for (int ftl = 0; ftl < 2; ++ftl) {
      const int f0 = (wv * 2 + ftl) * 16;
      const size_t wo = (size_t)(f0 + c) * NE + ks * 32 + g * 8;
      s8v qh, ql, kh, kl, vh, vl;
      split8(Wq + wo, CSCALE, qh, ql);
      split8(Wk + wo, 1.0f,   kh, kl);
      split8(Wv + wo, 1.0f,   vh, vl);
      #pragma unroll
      for (int st = 0; st < 4; ++st) {
        // Q (swapped operands -> C[s][f], like K)
        aq[ftl][st] = __builtin_amdgcn_mfma_f32_16x16x32_bf16(xbh[st], qh, aq[ftl][st], 0, 0, 0);
        aq[ftl][st] = __builtin_amdgcn_mfma_f32_16x16x32_bf16(xbl[st], qh, aq[ftl][st], 0, 0, 0);
        aq[ftl][st] = __builtin_amdgcn_mfma_f32_16x16x32_bf16(xbh[st], ql, aq[ftl][st], 0, 0, 0);
        // V (C[f][s])
        av[ftl][st] = __builtin_amdgcn_mfma_f32_16x16x32_bf16(vh, xbh[st], av[ftl][st], 0, 0, 0);
        av[ftl][st] = __builtin_amdgcn_mfma_f32_16x16x32_bf16(vh, xbl[st], av[ftl][st], 0, 0, 0);
        av[ftl][st] = __builtin_amdgcn_mfma_f32_16x16x32_bf16(vl, xbh[st], av[ftl][st], 0, 0, 0);
        // K (C[s][f])
        ak[ftl][st] = __builtin_amdgcn_mfma_f32_16x16x32_bf16(xbh[st], kh, ak[ftl][st], 0, 0, 0);
        ak[ftl][st] = __builtin_amdgcn_mfma_f32_16x16x32_bf16(xbl[st], kh, ak[ftl][st], 0, 0, 0);
        ak[ftl][st] = __builtin_amdgcn_mfma_f32_16x16x32_bf16(xbh[st], kl, ak[ftl][st], 0, 0, 0);
      }
    }
  }

  ushort* Qnb = Qn + (size_t)b * NS * NE;
  ushort* Knb = Kn + (size_t)b * NS * NE;
  ushort* Vtb = Vt + (size_t)b * NE * NS;
  #pragma unroll
  for (int ftl = 0; ftl < 2; ++ftl) {
    const int f0 = (wv * 2 + ftl) * 16;
    #pragma unroll
    for (int r = 0; r < 4; ++r) {            // V: row f = f0+4g+r, col s
      const int f = f0 + 4 * g + r;
      const float bvv = bv[f];
      #pragma unroll
      for (int st = 0; st < 4; ++st)
        Vtb[(size_t)f * NS + s0 + st * 16 + c] = f2bf(av[ftl][st][r] + bvv);
    }
    const float bqv = bq[f0 + c] * CSCALE;   // Q,K: row s = s0+st*16+4g+r, col f = f0+c
    const float bkv = bk[f0 + c];
    #pragma unroll
    for (int st = 0; st < 4; ++st)
      #pragma unroll
      for (int r = 0; r < 4; ++r) {
        const size_t ro = (size_t)(s0 + st * 16 + 4 * g + r) * NE + f0 + c;
        Qnb[ro] = f2bf(aq[ftl][st][r] + bqv);
        Knb[ro] = f2bf(ak[ftl][st][r] + bkv);
      }
  }
}

// ------- flash attention: 32x32 MFMA, QW=64, in-block k-split=2 ------------
// 4 waves: waves {0,1} = k-slice 0, waves {2,3} = k-slice 1, same 128 q.
// Each slice streams its own dbuf K/V LDS tiles; combine via LDS at the end.
__global__ __launch_bounds__(256, 1) void attn_kernel(
    const ushort* __restrict__ Qn, const ushort* __restrict__ Kn,
    const ushort* __restrict__ Vt, float* __restrict__ out)
{
  const int tid = threadIdx.x;
  const int wv = tid >> 6, lane = tid & 63;
  const int h = lane >> 5, q5 = lane & 31;
  const int slice = wv >> 1;                   // k-slice of this wave
  const int ws = wv & 1;                       // q-strip within block
  const int bid = blockIdx.x;
  const int b = bid & 7;                       // XCD pin: batch b -> XCD b
  const int qw = (bid >> 3) * 128 + ws * 64;   // wave's 64-q strip

  const ushort* Qb = Qn + (size_t)b * NS * NE;
  const char*   Kb = (const char*)(Kn + (size_t)b * NS * NE);
  const char*   Vb = (const char*)(Vt + (size_t)b * NE * NS);

  __shared__ __align__(16) char ldsK[2][2][16384];  // [slice][dbuf] K [64k][128d] (xor16)
  __shared__ __align__(16) char ldsV[2][2][16384];  // [slice][dbuf] V^T [128d][64k] (xor8)
  __shared__ float lx[2][2][32];                    // [ws][A/B][q5] slice-1 lsum

  // Q B-frags: lane holds Q[qw + u*32 + q5][d = dc*16 + h*8 + j]
  s8v qf[2][8];
  #pragma unroll
  for (int u = 0; u < 2; ++u)
    #pragma unroll
    for (int dc = 0; dc < 8; ++dc)
      qf[u][dc] = *(const s8v*)(Qb + (size_t)(qw + u * 32 + q5) * NE + dc * 16 + h * 8);

  // stage tile t of own slice into dbuf buf (2 waves cover 16KB each of K,V)
  auto stage = [&](int buf, int t) {
    const int kt = slice * 32 + t;
    const char* Ksrc = Kb + (size_t)kt * (64 * 256);   // contiguous 16KB
    #pragma unroll
    for (int p = 0; p < 8; ++p) {
      const int off = ws * 8192 + p * 1024;            // wave-uniform dest
      const int lo = off + lane * 16;
      const int row = lo >> 8;
      gload_lds16(Ksrc + (lo ^ ((row & 15) << 4)), &ldsK[slice][buf][off]);
    }
    #pragma unroll
    for (int p = 0; p < 8; ++p) {
      const int off = ws * 8192 + p * 1024;
      const int lo = off + lane * 16;
      const int row = lo >> 7;                         // d (128B rows)
      const int inner = (lo & 127) ^ ((row & 7) << 4);
      gload_lds16(Vb + (size_t)row * (NS * 2) + kt * 128 + inner, &ldsV[slice][buf][off]);
    }
  };

  auto makefrag = [&](const float* p, int r0) -> s8v {
    u32 A = cvtpk(p[r0 + 0], p[r0 + 1]);
    u32 B = cvtpk(p[r0 + 4], p[r0 + 5]);
    u32 C = cvtpk(p[r0 + 2], p[r0 + 3]);
    u32 D = cvtpk(p[r0 + 6], p[r0 + 7]);
    u2v rAB = __builtin_amdgcn_permlane32_swap(A, B, false, false);
    u2v rCD = __builtin_amdgcn_permlane32_swap(C, D, false, false);
    union { s8v v; u32 w[4]; } P;
    P.w[0] = rAB[0]; P.w[1] = rCD[0]; P.w[2] = rAB[1]; P.w[3] = rCD[1];
    return P.v;
  };

  f16v oA[4], oB[4];
  #pragma unroll
  for (int dt = 0; dt < 4; ++dt) {
    oA[dt] = (f16v){0,0,0,0,0,0,0,0,0,0,0,0,0,0,0,0};
    oB[dt] = (f16v){0,0,0,0,0,0,0,0,0,0,0,0,0,0,0,0};
  }
  float lA = 0.f, lB = 0.f;

  stage(0, 0);
  asm volatile("s_waitcnt vmcnt(0)" ::: "memory");
  __syncthreads();

  #pragma unroll 1
  for (int t = 0; t < 32; ++t) {
    const int cur = t & 1;
    if (t + 1 < 32) stage(cur ^ 1, t + 1);
    const char* bK = ldsK[slice][cur];
    const char* bV = ldsV[slice][cur];

    #pragma unroll
    for (int kc = 0; kc < 2; ++kc) {
      // ---- S^T[k][q] = K . Q^T for both q-subtiles (K frag shared)
      f16v sA = (f16v){0,0,0,0,0,0,0,0,0,0,0,0,0,0,0,0};
      f16v sB = (f16v){0,0,0,0,0,0,0,0,0,0,0,0,0,0,0,0};
      #pragma unroll
      for (int dc = 0; dc < 8; ++dc) {
        s8v kf = *(const s8v*)(bK + (kc * 32 + q5) * 256 + ((dc * 32 + h * 16) ^ ((q5 & 15) << 4)));
        sA = __builtin_amdgcn_mfma_f32_32x32x16_bf16(kf, qf[0][dc], sA, 0, 0, 0);
        sB = __builtin_amdgcn_mfma_f32_32x32x16_bf16(kf, qf[1][dc], sB, 0, 0, 0);
      }
      // ---- P = exp2(S), denominators
      float pA[16], pB[16];
      #pragma unroll
      for (int r = 0; r < 16; ++r) {
        pA[r] = __builtin_amdgcn_exp2f(sA[r]); lA += pA[r];
        pB[r] = __builtin_amdgcn_exp2f(sB[r]); lB += pB[r];
      }
      // ---- PV: V frag shared by both q-subtiles
      #pragma unroll
      for (int ksl = 0; ksl < 2; ++ksl) {
        s8v PA = makefrag(pA, ksl * 8);
        s8v PB = makefrag(pB, ksl * 8);
        const int ks = kc * 2 + ksl;
        #pragma unroll
        for (int dt = 0; dt < 4; ++dt) {
          s8v vf = *(const s8v*)(bV + (dt * 32 + q5) * 128 + ((ks * 32 + h * 16) ^ ((q5 & 7) << 4)));
          oA[dt] = __builtin_amdgcn_mfma_f32_32x32x16_bf16(vf, PA, oA[dt], 0, 0, 0);
          oB[dt] = __builtin_amdgcn_mfma_f32_32x32x16_bf16(vf, PB, oB[dt], 0, 0, 0);
        }
      }
    }
    asm volatile("s_waitcnt vmcnt(0)" ::: "memory");  // next tile fully in LDS
    __syncthreads();
  }

  // ---- in-block k-slice combine (reuse ldsK region, 64 KB = 2 x 8192 f32) --
  lA += __shfl_xor(lA, 32);
  lB += __shfl_xor(lB, 32);
  float* cb = (float*)&ldsK[0][0][0];
  if (slice == 1) {
    #pragma unroll
    for (int dt = 0; dt < 4; ++dt)
      #pragma unroll
      for (int r = 0; r < 16; ++r) {
        cb[ws * 8192 + (dt * 16 + r) * 64 + lane]      = oA[dt][r];
        cb[ws * 8192 + (64 + dt * 16 + r) * 64 + lane] = oB[dt][r];
      }
    if (h == 0) { lx[ws][0][q5] = lA; lx[ws][1][q5] = lB; }
  }
  __syncthreads();
  if (slice == 0) {
    const float rA = 1.0f / (lA + lx[ws][0][q5]);
    const float rB = 1.0f / (lB + lx[ws][1][q5]);
    float* ob = out + (size_t)b * NE * NS;
    #pragma unroll
    for (int dt = 0; dt < 4; ++dt)
      #pragma unroll
      for (int r = 0; r < 16; ++r) {
        const int e = dt * 32 + (r & 3) + 8 * (r >> 2) + 4 * h;
        ob[(size_t)e * NS + qw + q5] =
            (oA[dt][r] + cb[ws * 8192 + (dt * 16 + r) * 64 + lane]) * rA;
        ob[(size_t)e * NS + qw + 32 + q5] =
            (oB[dt][r] + cb[ws * 8192 + (64 + dt * 16 + r) * 64 + lane]) * rB;
      }
  }
}

extern "C" void kernel_launch(void* const* d_in, const int* in_sizes, int n_in,
                              void* d_out, int out_size, void* d_ws, size_t ws_size,
                              hipStream_t stream) {
  (void)in_sizes; (void)n_in; (void)out_size; (void)ws_size;
  const float* x  = (const float*)d_in[0];
  const float* Wq = (const float*)d_in[1];
  const float* bq = (const float*)d_in[2];
  const float* Wk = (const float*)d_in[3];
  const float* bk = (const float*)d_in[4];
  const float* Wv = (const float*)d_in[5];
  const float* bv = (const float*)d_in[6];
  float* out = (float*)d_out;

  ushort* Qn = (ushort*)d_ws;                      // [B][S][D] bf16, 8 MB
  ushort* Kn = Qn + (size_t)NB * NS * NE;          // [B][S][D] bf16, 8 MB
  ushort* Vt = Kn + (size_t)NB * NS * NE;          // [B][D][S] bf16, 8 MB

  proj_gemm<<<dim3(NS / 64 * NB), 256, 0, stream>>>(x, Wq, bq, Wk, bk, Wv, bv, Qn, Kn, Vt);
  attn_kernel<<<dim3(NS / 128 * NB), 256, 0, stream>>>(Qn, Kn, Vt, out);
}